// Round 3
// baseline (172.543 us; speedup 1.0000x reference)
//
#include <hip/hip_runtime.h>
#include <math.h>

#define NN 1024
#define B_C 64
#define L_C 160000
#define T_C 622
#define F_C 513
#define TT 16
#define NTILE ((T_C + TT - 1) / TT)   // 39
#define WIN_MIN_C (1024.0f / 20.0f)
#define WIN_MAX_C 1024.0f
#define TWO_PI 6.28318530717958647692f

__device__ __forceinline__ int brev6(int x) {
    return ((x & 1) << 5) | ((x & 2) << 3) | ((x & 4) << 1) |
           ((x & 8) >> 1) | ((x & 16) >> 3) | ((x & 32) >> 5);
}

// ---------------- Kernel A: per-frame normalized Hann taps ----------------
__global__ __launch_bounds__(256) void win_kernel(
    const float* __restrict__ win_length,
    const float* __restrict__ strides,
    const float* __restrict__ win_pow,
    float* __restrict__ tap)   // [T_C][NN]
{
    const int t = blockIdx.x;
    const int tid = threadIdx.x;

    const float wl = fminf(fmaxf(win_length[0], WIN_MIN_C), WIN_MAX_C);
    const float st = fminf(fmaxf(strides[0], 0.0f), WIN_MAX_C);
    const float wp = win_pow[0];

    const float frame = (float)t * st;
    const float frac = frame - floorf(frame);

    const float hi = ceilf(((float)NN - 1.0f + wl) * 0.5f);
    const float lo = floorf(((float)NN - 1.0f - wl) * 0.5f);
    const float off = (wl - (float)NN + 1.0f) * 0.5f;
    const float inv_wl = 1.0f / wl;

    __shared__ float s_tap[NN];
    __shared__ float s_red[256];

    float local = 0.0f;
    for (int n = tid; n < NN; n += 256) {
        float base = (float)n - frac;
        float v = 0.5f - 0.5f * cosf(TWO_PI * (base + off) * inv_wl);
        if (base >= hi || base <= lo) v = 0.0f;
        s_tap[n] = v;
        local += v;
    }
    s_red[tid] = local;
    __syncthreads();
    for (int s = 128; s > 0; s >>= 1) {
        if (tid < s) s_red[tid] += s_red[tid + s];
        __syncthreads();
    }
    const float inv_sum = 1.0f / s_red[0];
    const bool pow_one = (wp == 1.0f);
    for (int n = tid; n < NN; n += 256) {
        float v = s_tap[n] * inv_sum;
        if (!pow_one) v = powf(v, wp);
        tap[t * NN + n] = v;
    }
}

// --- Kernel B: wave-per-packed-FFT, registers + shfl, 1 barrier total ---
__global__ __launch_bounds__(256) void fftw_kernel(
    const float* __restrict__ x,        // [B_C][L_C]
    const float* __restrict__ strides,
    const float* __restrict__ tap,      // [T_C][NN]
    float* __restrict__ out)            // [B_C][F_C][T_C]
{
    const int tile = blockIdx.x % NTILE;
    const int b = blockIdx.x / NTILE;
    const int t0 = tile * TT;
    const int tid = threadIdx.x;
    const int w = tid >> 6;      // wave id 0..3
    const int l = tid & 63;      // lane

    const float st = fminf(fmaxf(strides[0], 0.0f), WIN_MAX_C);
    const float* xb = x + (size_t)b * L_C;

    __shared__ float mag[TT][F_C + 16];   // row = 529 floats (pad vs bank conflicts)

    const int bl = brev6(l);
    const int l2 = brev6((64 - bl) & 63);   // unpack partner lane for k1==0 reg

    // compile-time tables
    constexpr int BR4[16]     = {0,8,4,12,2,10,6,14,1,9,5,13,3,11,7,15};
    constexpr int PARTNER[16] = {0,1,3,2,7,6,5,4,15,14,13,12,11,10,9,8};
    constexpr float C16[8] = {1.0f, 0.92387953251f, 0.70710678119f, 0.38268343236f,
                              0.0f, -0.38268343236f, -0.70710678119f, -0.92387953251f};
    constexpr float S16[8] = {0.0f, -0.38268343236f, -0.70710678119f, -0.92387953251f,
                              -1.0f, -0.92387953251f, -0.70710678119f, -0.38268343236f};

    for (int q = 0; q < 2; ++q) {
        const int jp = q * 4 + w;           // pair index 0..7
        const int tA = t0 + 2 * jp;
        const int tB = tA + 1;
        const bool hasA = (tA < T_C);
        const bool hasB = (tB < T_C);
        const int idxA = hasA ? (int)floorf((float)tA * st) : 0;
        const int idxB = hasB ? (int)floorf((float)tB * st) : 0;
        const float* tpA = tap + (size_t)tA * NN;
        const float* tpB = tap + (size_t)tB * NN;

        float vr[16], vi[16];

        // ---- load + taper: frame A -> re, frame B -> im; element n = 64*r + l
#pragma unroll
        for (int r = 0; r < 16; ++r) {
            const int n = r * 64 + l;
            float a = 0.0f, bb = 0.0f;
            if (hasA) {
                int ia = idxA + n;
                a = (ia >= 0 && ia < L_C) ? xb[ia] * tpA[n] : 0.0f;
            }
            if (hasB) {
                int ib = idxB + n;
                bb = (ib >= 0 && ib < L_C) ? xb[ib] * tpB[n] : 0.0f;
            }
            vr[r] = a;
            vi[r] = bb;
        }

        // ---- 16-point DIF FFT over registers (output i holds k1 = BR4[i])
#pragma unroll
        for (int s = 0; s < 4; ++s) {
            const int size = 16 >> s;
            const int half = size >> 1;
#pragma unroll
            for (int b0 = 0; b0 < 16; b0 += (16 >> s)) {
#pragma unroll
                for (int j = 0; j < 8; ++j) {
                    if (j < half) {
                        const int i0 = b0 + j, i1 = b0 + j + half;
                        const float ur = vr[i0], ui = vi[i0];
                        const float wr = vr[i1], wi = vi[i1];
                        vr[i0] = ur + wr; vi[i0] = ui + wi;
                        const float dr = ur - wr, di = ui - wi;
                        const float c = C16[j << s], ss = S16[j << s];
                        vr[i1] = dr * c - di * ss;
                        vi[i1] = dr * ss + di * c;
                    }
                }
            }
        }

        // ---- twiddle W_1024^(l * k1)
        const float thl = -(TWO_PI / 1024.0f) * (float)l;
#pragma unroll
        for (int i = 0; i < 16; ++i) {
            const int k1 = BR4[i];
            if (k1 > 0) {
                float sv, cv;
                __sincosf(thl * (float)k1, &sv, &cv);
                const float ar = vr[i], ai = vi[i];
                vr[i] = ar * cv - ai * sv;
                vi[i] = ar * sv + ai * cv;
            }
        }

        // ---- 64-point DIF FFT across lanes (6 shfl_xor stages)
#pragma unroll
        for (int s = 0; s < 6; ++s) {
            const int half = 32 >> s;
            const bool low = (l & (2 * half - 1)) < half;
            const int j = l & (half - 1);
            float sv, cv;
            __sincosf(-(TWO_PI * (float)j) / (float)(2 * half), &sv, &cv);
            const float tc = low ? 1.0f : cv;
            const float ts = low ? 0.0f : sv;
#pragma unroll
            for (int i = 0; i < 16; ++i) {
                const float pr = __shfl_xor(vr[i], half, 64);
                const float pi = __shfl_xor(vi[i], half, 64);
                const float sr = low ? (vr[i] + pr) : (pr - vr[i]);
                const float si = low ? (vi[i] + pi) : (pi - vi[i]);
                vr[i] = sr * tc - si * ts;
                vi[i] = sr * ts + si * tc;
            }
        }
        // now (lane l, reg i) holds X[k], k = BR4[i] + 16*brev6(l)

        // ---- conjugate-symmetry unpack + magnitudes -> mag LDS
#pragma unroll
        for (int i = 0; i < 16; ++i) {
            const int k1 = BR4[i];
            float yr, yi;
            if (k1 == 0) {
                yr = __shfl(vr[0], l2, 64);
                yi = __shfl(vi[0], l2, 64);
            } else {
                yr = __shfl_xor(vr[PARTNER[i]], 63, 64);
                yi = __shfl_xor(vi[PARTNER[i]], 63, 64);
            }
            const int k = k1 + 16 * bl;
            if (k <= 512) {
                const float zr = vr[i], zi = vi[i];
                const float xar = 0.5f * (zr + yr), xai = 0.5f * (zi - yi);
                const float xbr = 0.5f * (zi + yi), xbi = 0.5f * (yr - zr);
                const int ka = k + (k >> 5);
                if (hasA) mag[2 * jp][ka] = sqrtf(xar * xar + xai * xai);
                if (hasB) mag[2 * jp + 1][ka] = sqrtf(xbr * xbr + xbi * xbi);
            }
        }
    }

    __syncthreads();

    // ---- coalesced write-out: rows of 16 consecutive t per f
    for (int e = tid; e < F_C * TT; e += 256) {
        const int f = e >> 4;
        const int tt = e & 15;
        const int t = t0 + tt;
        if (t < T_C)
            out[((size_t)b * F_C + f) * T_C + t] = mag[tt][f + (f >> 5)];
    }
}

extern "C" void kernel_launch(void* const* d_in, const int* in_sizes, int n_in,
                              void* d_out, int out_size, void* d_ws, size_t ws_size,
                              hipStream_t stream) {
    const float* x   = (const float*)d_in[0];
    const float* wl  = (const float*)d_in[1];
    const float* st  = (const float*)d_in[2];
    const float* wp  = (const float*)d_in[3];
    float* out = (float*)d_out;
    float* tap = (float*)d_ws;   // T_C*NN floats ~ 2.55 MB

    win_kernel<<<dim3(T_C), dim3(256), 0, stream>>>(wl, st, wp, tap);
    fftw_kernel<<<dim3(B_C * NTILE), dim3(256), 0, stream>>>(x, st, tap, out);
}

// Round 4
// 108.920 us; speedup vs baseline: 1.5841x; 1.5841x over previous
//
#include <hip/hip_runtime.h>
#include <math.h>

#define NN 1024
#define B_C 64
#define L_C 160000
#define T_C 622
#define F_C 513
#define TT 16
#define NTILE ((T_C + TT - 1) / TT)   // 39
#define WIN_MIN_C (1024.0f / 20.0f)
#define WIN_MAX_C 1024.0f
#define TWO_PI 6.28318530717958647692f

__device__ __forceinline__ int brev6(int x) {
    return ((x & 1) << 5) | ((x & 2) << 3) | ((x & 4) << 1) |
           ((x & 8) >> 1) | ((x & 16) >> 3) | ((x & 32) >> 5);
}

// xor-32 lane partner: VALU permlane32_swap when available, else DS shuffle
__device__ __forceinline__ float xor32_partner(float v, int lane) {
#if __has_builtin(__builtin_amdgcn_permlane32_swap)
    typedef unsigned uv2 __attribute__((ext_vector_type(2)));
    uv2 r = __builtin_amdgcn_permlane32_swap(__float_as_uint(v), __float_as_uint(v),
                                             false, false);
    return (lane < 32) ? __uint_as_float(r.y) : __uint_as_float(r.x);
#else
    return __shfl_xor(v, 32, 64);
#endif
}

// ---------------- Kernel A: per-frame normalized Hann taps ----------------
__global__ __launch_bounds__(256) void win_kernel(
    const float* __restrict__ win_length,
    const float* __restrict__ strides,
    const float* __restrict__ win_pow,
    float* __restrict__ tap)   // [T_C][NN]
{
    const int t = blockIdx.x;
    const int tid = threadIdx.x;

    const float wl = fminf(fmaxf(win_length[0], WIN_MIN_C), WIN_MAX_C);
    const float st = fminf(fmaxf(strides[0], 0.0f), WIN_MAX_C);
    const float wp = win_pow[0];

    const float frame = (float)t * st;
    const float frac = frame - floorf(frame);

    const float hi = ceilf(((float)NN - 1.0f + wl) * 0.5f);
    const float lo = floorf(((float)NN - 1.0f - wl) * 0.5f);
    const float off = (wl - (float)NN + 1.0f) * 0.5f;
    const float inv_wl = 1.0f / wl;

    __shared__ float s_tap[NN];
    __shared__ float s_red[256];

    float local = 0.0f;
    for (int n = tid; n < NN; n += 256) {
        float base = (float)n - frac;
        float v = 0.5f - 0.5f * cosf(TWO_PI * (base + off) * inv_wl);
        if (base >= hi || base <= lo) v = 0.0f;
        s_tap[n] = v;
        local += v;
    }
    s_red[tid] = local;
    __syncthreads();
    for (int s = 128; s > 0; s >>= 1) {
        if (tid < s) s_red[tid] += s_red[tid + s];
        __syncthreads();
    }
    const float inv_sum = 1.0f / s_red[0];
    const bool pow_one = (wp == 1.0f);
    for (int n = tid; n < NN; n += 256) {
        float v = s_tap[n] * inv_sum;
        if (!pow_one) v = powf(v, wp);
        tap[t * NN + n] = v;
    }
}

// --- Kernel B: 8 waves/block, wave-per-packed-FFT, registers + shfl ---
__global__ __launch_bounds__(512) void fftw_kernel(
    const float* __restrict__ x,        // [B_C][L_C]
    const float* __restrict__ strides,
    const float* __restrict__ tap,      // [T_C][NN]
    float* __restrict__ out)            // [B_C][F_C][T_C]
{
    const int tile = blockIdx.x % NTILE;
    const int b = blockIdx.x / NTILE;
    const int t0 = tile * TT;
    const int tid = threadIdx.x;
    const int w = tid >> 6;      // wave id 0..7 = frame pair
    const int l = tid & 63;      // lane

    const float st = fminf(fmaxf(strides[0], 0.0f), WIN_MAX_C);
    const float* xb = x + (size_t)b * L_C;

    __shared__ float mag[TT][F_C + 16];   // 529-float rows (bank-conflict pad)

    const int bl = brev6(l);
    const int l2 = brev6((64 - bl) & 63);   // unpack partner lane for k1==0 reg

    constexpr int BR4[16]     = {0,8,4,12,2,10,6,14,1,9,5,13,3,11,7,15};
    constexpr int PARTNER[16] = {0,1,3,2,7,6,5,4,15,14,13,12,11,10,9,8};
    constexpr float C16[8] = {1.0f, 0.92387953251f, 0.70710678119f, 0.38268343236f,
                              0.0f, -0.38268343236f, -0.70710678119f, -0.92387953251f};
    constexpr float S16[8] = {0.0f, -0.38268343236f, -0.70710678119f, -0.92387953251f,
                              -1.0f, -0.92387953251f, -0.70710678119f, -0.38268343236f};

    const int jp = w;                   // pair index 0..7
    const int tA = t0 + 2 * jp;
    const int tB = tA + 1;
    const bool hasA = (tA < T_C);
    const bool hasB = (tB < T_C);
    const int idxA = hasA ? (int)floorf((float)tA * st) : 0;
    const int idxB = hasB ? (int)floorf((float)tB * st) : 0;
    const float* tpA = tap + (size_t)tA * NN;
    const float* tpB = tap + (size_t)tB * NN;

    float vr[16], vi[16];

    // ---- load + taper: frame A -> re, frame B -> im; element n = 64*r + l
#pragma unroll
    for (int r = 0; r < 16; ++r) {
        const int n = r * 64 + l;
        float a = 0.0f, bb = 0.0f;
        if (hasA) {
            int ia = idxA + n;
            a = (ia >= 0 && ia < L_C) ? xb[ia] * tpA[n] : 0.0f;
        }
        if (hasB) {
            int ib = idxB + n;
            bb = (ib >= 0 && ib < L_C) ? xb[ib] * tpB[n] : 0.0f;
        }
        vr[r] = a;
        vi[r] = bb;
    }

    // ---- 16-point DIF FFT over registers (output i holds k1 = BR4[i])
#pragma unroll
    for (int s = 0; s < 4; ++s) {
        const int half = (16 >> s) >> 1;
#pragma unroll
        for (int b0 = 0; b0 < 16; b0 += (16 >> s)) {
#pragma unroll
            for (int j = 0; j < 8; ++j) {
                if (j < half) {
                    const int i0 = b0 + j, i1 = b0 + j + half;
                    const float ur = vr[i0], ui = vi[i0];
                    const float wr = vr[i1], wi = vi[i1];
                    vr[i0] = ur + wr; vi[i0] = ui + wi;
                    const float dr = ur - wr, di = ui - wi;
                    const float c = C16[j << s], ss = S16[j << s];
                    vr[i1] = dr * c - di * ss;
                    vi[i1] = dr * ss + di * c;
                }
            }
        }
    }

    // ---- twiddle W_1024^(l * k1) via 1 sincos + complex recurrence
    {
        float w1i, w1r;
        __sincosf(-(TWO_PI / 1024.0f) * (float)l, &w1i, &w1r);
        float cwr = w1r, cwi = w1i;                 // w^1
#pragma unroll
        for (int k1 = 1; k1 < 16; ++k1) {
            const int i = BR4[k1];                  // reg holding this k1
            const float ar = vr[i], ai = vi[i];
            vr[i] = ar * cwr - ai * cwi;
            vi[i] = ar * cwi + ai * cwr;
            const float nr = cwr * w1r - cwi * w1i;
            const float ni = cwr * w1i + cwi * w1r;
            cwr = nr; cwi = ni;
        }
    }

    // ---- 64-point DIF FFT across lanes (6 stages; stage 0 via permlane)
#pragma unroll
    for (int s = 0; s < 6; ++s) {
        const int half = 32 >> s;
        const bool low = (l & (2 * half - 1)) < half;
        const int j = l & (half - 1);
        float sv, cv;
        __sincosf(-(TWO_PI * (float)j) / (float)(2 * half), &sv, &cv);
        const float tc = low ? 1.0f : cv;
        const float ts = low ? 0.0f : sv;
#pragma unroll
        for (int i = 0; i < 16; ++i) {
            float pr, pi;
            if (s == 0) {
                pr = xor32_partner(vr[i], l);
                pi = xor32_partner(vi[i], l);
            } else {
                pr = __shfl_xor(vr[i], half, 64);
                pi = __shfl_xor(vi[i], half, 64);
            }
            const float sr = low ? (vr[i] + pr) : (pr - vr[i]);
            const float si = low ? (vi[i] + pi) : (pi - vi[i]);
            vr[i] = sr * tc - si * ts;
            vi[i] = sr * ts + si * tc;
        }
    }
    // now (lane l, reg i) holds X[k], k = BR4[i] + 16*brev6(l)

    // ---- conjugate-symmetry unpack + magnitudes -> mag LDS
#pragma unroll
    for (int i = 0; i < 16; ++i) {
        const int k1 = BR4[i];
        float yr, yi;
        if (k1 == 0) {
            yr = __shfl(vr[0], l2, 64);
            yi = __shfl(vi[0], l2, 64);
        } else {
            yr = __shfl_xor(vr[PARTNER[i]], 63, 64);
            yi = __shfl_xor(vi[PARTNER[i]], 63, 64);
        }
        const int k = k1 + 16 * bl;
        if (k <= 512) {
            const float zr = vr[i], zi = vi[i];
            const float xar = 0.5f * (zr + yr), xai = 0.5f * (zi - yi);
            const float xbr = 0.5f * (zi + yi), xbi = 0.5f * (yr - zr);
            const int ka = k + (k >> 5);
            if (hasA) mag[2 * jp][ka] = sqrtf(xar * xar + xai * xai);
            if (hasB) mag[2 * jp + 1][ka] = sqrtf(xbr * xbr + xbi * xbi);
        }
    }

    __syncthreads();

    // ---- coalesced write-out: rows of 16 consecutive t per f
    for (int e = tid; e < F_C * TT; e += 512) {
        const int f = e >> 4;
        const int tt = e & 15;
        const int t = t0 + tt;
        if (t < T_C)
            out[((size_t)b * F_C + f) * T_C + t] = mag[tt][f + (f >> 5)];
    }
}

extern "C" void kernel_launch(void* const* d_in, const int* in_sizes, int n_in,
                              void* d_out, int out_size, void* d_ws, size_t ws_size,
                              hipStream_t stream) {
    const float* x   = (const float*)d_in[0];
    const float* wl  = (const float*)d_in[1];
    const float* st  = (const float*)d_in[2];
    const float* wp  = (const float*)d_in[3];
    float* out = (float*)d_out;
    float* tap = (float*)d_ws;   // T_C*NN floats ~ 2.55 MB

    win_kernel<<<dim3(T_C), dim3(256), 0, stream>>>(wl, st, wp, tap);
    fftw_kernel<<<dim3(B_C * NTILE), dim3(512), 0, stream>>>(x, st, tap, out);
}